// Round 10
// baseline (132.778 us; speedup 1.0000x reference)
//
#include <hip/hip_runtime.h>
#include <stdint.h>

// Problem: out[m,e,k] = sum_n A[m,n] * W[e,n,k]
// == GEMM C[8192,2048] = A[8192,1024] x B[1024,2048], B[n, e*32+k] = W[e,n,k]
//
// Round-14 structure: the untested quadrant {good pipeline x high occupancy}.
// Eliminated by A/B so far: schedule (7 variants flat), LDS BW (halved, null),
// occupancy-with-bad-schedule (r7: worse), HBM/L2 traffic (r9: FETCH 68->24.6
// MB, null). All fast variants ran 2 waves/SIMD (~248 unified regs); r7's
// 4/SIMD had syncthreads-vmcnt(0) drains + j-slice fetch amplification.
// This round: wave tile 64x64 (acc 64 AGPR), block 128x128 / 4 waves, frags
// 64 VGPR -> ~140 unified regs -> 3-4 waves/SIMD; grid 1024 = 3-4 blocks/CU
// (staggered barriers). Keep counted-vmcnt raw-barrier pipeline (B prefetched
// cross-barrier, staging issue-early, never vm(0) mid-loop) + M-slice XCD
// (xcd owns 8 m-tiles = 2 MB A, L2-resident; B j-slab 256 KB L2-hot).
// Fragment loads are plain C++ (compiler guarantees their data deps); hand
// waits are load-bearing only for GLDS staging (vm(4)@c1 + fence + barrier).
// Ledger/tile: entry bfA(4) -> c0: af(h0) ds4, stage4, bfB4; lgkm0, vm(8)
// [bfA ready] -> MFMA16 -> c1: af(h1) ds4, bfA'4; lgkm0, vm(4) [stage+bfB
// drained, bfA' in flight] -> MFMA16 -> fence, barrier, swap. Tail peeled.
// A LDS: [128 rows][8 grp][8] XOR-swizzled (grp ^ row&7), conflict-free.

#define M_DIM 8192
#define N_IN  1024   // reduction dim
#define E_DIM 64
#define K_DIM 32
#define J_DIM 2048   // E*K output columns

typedef __attribute__((ext_vector_type(8))) __bf16 bf16x8;
typedef __attribute__((ext_vector_type(4))) float floatx4;
typedef __attribute__((address_space(3))) unsigned short lds_u16;

__device__ inline unsigned short f2bf(float f) {
    union { float f; unsigned u; } v; v.f = f;
    unsigned u = v.u;
    u += 0x7fff + ((u >> 16) & 1);   // round-to-nearest-even
    return (unsigned short)(u >> 16);
}

// A [8192,1024] f32 -> Ab bf16 (same row-major layout). 4 elements/thread.
__global__ __launch_bounds__(256) void convert_A(const float* __restrict__ A,
                                                 unsigned short* __restrict__ Ab) {
    size_t i = (size_t)blockIdx.x * 256 + threadIdx.x;
    const float4 v = ((const float4*)A)[i];
    ushort4 o;
    o.x = f2bf(v.x); o.y = f2bf(v.y); o.z = f2bf(v.z); o.w = f2bf(v.w);
    ((ushort4*)Ab)[i] = o;
}

// W [64][1024][32] f32 -> BG[kgroup=n>>3][j=e*32+k][t=n&7] bf16  (128 x 2048 x 8).
// B fragment for 16x16x32 MFMA: lane holds B^T[col j][k = kgroup*8 + t], t=0..7
// contiguous -> one 16B load per lane, lanes j-consecutive -> coalesced.
__global__ __launch_bounds__(256) void convert_W(const float* __restrict__ W,
                                                 unsigned short* __restrict__ BG) {
    const int t   = threadIdx.x;
    const int e   = blockIdx.y;        // 0..63
    const int n0  = blockIdx.x * 64;   // 16 slabs
    const int k   = t & 31;
    const int oct = t >> 5;            // 8 octets of n within the slab
    const float* Wp = W + ((size_t)e * N_IN + n0 + oct * 8) * K_DIM + k;
    unsigned short tmp[8];
#pragma unroll
    for (int u = 0; u < 8; ++u) tmp[u] = f2bf(Wp[(size_t)u * K_DIM]);  // coalesced per u
    unsigned short* out = BG + ((size_t)((n0 >> 3) + oct) * J_DIM + e * K_DIM + k) * 8;
    ushort4 lo, hi;
    lo.x = tmp[0]; lo.y = tmp[1]; lo.z = tmp[2]; lo.w = tmp[3];
    hi.x = tmp[4]; hi.y = tmp[5]; hi.z = tmp[6]; hi.w = tmp[7];
    ((ushort4*)out)[0] = lo;
    ((ushort4*)out)[1] = hi;
}

#define GLDS(SRC, DST)                                                          \
    __builtin_amdgcn_global_load_lds(                                           \
        (const __attribute__((address_space(1))) unsigned int*)(SRC),           \
        (__attribute__((address_space(3))) unsigned int*)(DST), 16, 0, 0)

// Stage the 128x64 A-slab of K-tile T1 into LDS buffer NA (16 chunks of 1 KB,
// 4 per wave). Lane l covers LDS slot (row=l>>3, grp=l&7), fetching
// pre-swizzled global group (l&7)^(l>>3).
#define STAGE_A(NA, T1)                                                         \
    { _Pragma("unroll")                                                         \
      for (int c = 0; c < 4; ++c)                                               \
          GLDS(gA0 + (size_t)c * (8 * N_IN) + (size_t)(T1) * 64,                \
               (NA) + wave * 2048 + c * 512); }

#define WAIT_VM(N) asm volatile("s_waitcnt vmcnt(" #N ")" ::: "memory")
#define LGKM(N)    asm volatile("s_waitcnt lgkmcnt(" #N ")" ::: "memory")
#define SB()       __builtin_amdgcn_sched_barrier(0)
#define MEMFENCE() asm volatile("" ::: "memory")

// A fragment loads (explicit LDS address space -> ds_read_b128).
#define RD_A(DST, CA, H)                                                        \
    { _Pragma("unroll")                                                         \
      for (int ii = 0; ii < 4; ++ii)                                            \
          DST[ii] = *(const __attribute__((address_space(3))) bf16x8*)          \
                    ((CA) + arow + ii * 1024 + (sA0 ^ ((H) << 5))); }

// B fragment loads DIRECT from global (L2-hot), kgroup KG, 4 j-subtiles.
#define RD_BG(DST, KG)                                                          \
    { _Pragma("unroll")                                                         \
      for (int j = 0; j < 4; ++j)                                               \
          DST[j] = *(const bf16x8*)(BG + ((size_t)(KG) * J_DIM + jcol + j * 16) * 8); }

// 16-MFMA cluster on register-resident fragments (T5 setprio wrap).
#define MFMA_CL(AF, BF)                                                         \
    { __builtin_amdgcn_s_setprio(1);                                            \
      _Pragma("unroll")                                                         \
      for (int ii = 0; ii < 4; ++ii) {                                          \
          _Pragma("unroll")                                                     \
          for (int j = 0; j < 4; ++j)                                           \
              acc[ii][j] = __builtin_amdgcn_mfma_f32_16x16x32_bf16(             \
                  AF[ii], BF[j], acc[ii][j], 0, 0, 0);                          \
      }                                                                         \
      __builtin_amdgcn_s_setprio(0); }

__global__ __launch_bounds__(256, 3) void gemm_bt(const unsigned short* __restrict__ Ab,
                                                  const unsigned short* __restrict__ BG,
                                                  float* __restrict__ C) {
    __shared__ unsigned short As0[8192];   // A tile buf0: [128 rows][8 grp][8]
    __shared__ unsigned short As1[8192];

    const int tid  = threadIdx.x;
    const int wave = tid >> 6;       // 0..3
    const int lane = tid & 63;
    const int wm = wave >> 1;        // 0..1  (M-half of 128)
    const int wn = wave & 1;         // 0..1  (N-half of 128)

    // M-slice XCD ownership: XCD x (= orig%8) owns m-tiles [8x, 8x+8):
    // A slice 8 x 128 rows x 2 KB = 2 MB -> L2-resident. j walks slowest.
    const int orig = blockIdx.x;     // 1024 blocks = 8 xcd x (8 m x 16 j)
    const int xcd  = orig & 7;
    const int s    = orig >> 3;
    const int m0 = (xcd * 8 + (s & 7)) * 128;
    const int j0 = (s >> 3) * 128;

    const int l7 = lane & 7, l15 = lane & 15, quad = lane >> 4, lrow8 = lane >> 3;

    // A staging base: rows m0 + wave*32 + c*8 + lrow8, pre-swizzled group.
    const unsigned short* gA0 = Ab + (size_t)(m0 + wave * 32 + lrow8) * N_IN
                                   + ((l7 ^ lrow8) << 3);
    const int jcol = j0 + wn * 64 + l15;      // per-lane B column

    lds_u16* cA = (lds_u16*)As0;
    lds_u16* nA = (lds_u16*)As1;

    floatx4 acc[4][4];
#pragma unroll
    for (int i = 0; i < 4; ++i)
#pragma unroll
        for (int j = 0; j < 4; ++j) acc[i][j] = (floatx4)(0.0f);

    // Fragment-read addressing (row&7 == l7 since rows step by 16).
    const int arow = (wm * 64 + l15) * 64;            // A row base (shorts)
    const int sA0  = (quad ^ l7) << 3;                // A slot-group; h flips bit 2

    bf16x8 afA[4], afB[4], bfA[4], bfB[4];

    // --- prologue: stage A(0); prefetch B(h0,0); barrier --------------------
    STAGE_A(cA, 0);
    RD_BG(bfA, quad);
    WAIT_VM(4);                       // staging done; bfA x4 in flight
    MEMFENCE();
    __builtin_amdgcn_s_barrier();
    MEMFENCE(); SB();

    // --- main loop: 15 tiles with staging + cross-barrier B prefetch --------
    for (int t = 0; t < 15; ++t) {
        // c0 (h0): issue af(h0) reads, stage A(t+1), prefetch B(h1,t)
        RD_A(afA, cA, 0);
        STAGE_A(nA, t + 1);
        RD_BG(bfB, t * 8 + 4 + quad);
        LGKM(0);                      // af(h0) ready
        WAIT_VM(8); SB();             // bfA ready (stage4 + bfB4 in flight)
        MFMA_CL(afA, bfA);

        // c1 (h1): issue af(h1) reads, prefetch B(h0,t+1)
        RD_A(afB, cA, 1);
        RD_BG(bfA, (t + 1) * 8 + quad);
        LGKM(0);                      // af(h1) ready
        WAIT_VM(4); SB();             // stage + bfB drained; bfA' in flight
        MFMA_CL(afB, bfB);

        // tile boundary: staging proven drained at c1's vm(4); own ds_reads
        // drained at c1's lgkm(0). bfA' (register dest) rides over the barrier.
        MEMFENCE();
        __builtin_amdgcn_s_barrier();
        MEMFENCE(); SB();
        lds_u16* sw = cA; cA = nA; nA = sw;
    }

    // --- tail tile 15 (no staging, no next-tile B) --------------------------
    RD_A(afA, cA, 0);
    RD_BG(bfB, 15 * 8 + 4 + quad);
    LGKM(0);
    WAIT_VM(4); SB();                 // bfA ready (bfB in flight)
    MFMA_CL(afA, bfA);
    RD_A(afB, cA, 1);
    LGKM(0);
    WAIT_VM(0); SB();                 // bfB ready
    MFMA_CL(afB, bfB);

    // Epilogue: C/D layout col = lane&15, row = (lane>>4)*4 + reg
    const int crow = quad * 4;
#pragma unroll
    for (int i = 0; i < 4; ++i) {
#pragma unroll
        for (int j = 0; j < 4; ++j) {
            float* Cp = C + (size_t)(m0 + wm * 64 + i * 16 + crow) * J_DIM
                          + (j0 + wn * 64 + j * 16 + l15);
#pragma unroll
            for (int r = 0; r < 4; ++r)
                Cp[(size_t)r * J_DIM] = acc[i][j][r];
        }
    }
}

extern "C" void kernel_launch(void* const* d_in, const int* in_sizes, int n_in,
                              void* d_out, int out_size, void* d_ws, size_t ws_size,
                              hipStream_t stream) {
    const float* A = (const float*)d_in[0];   // [8192,1024]
    const float* W = (const float*)d_in[1];   // [64,1024,32]
    float* out = (float*)d_out;               // [8192,64,32] == [8192,2048]

    unsigned short* Ab = (unsigned short*)d_ws;                 // 16 MB
    unsigned short* BG = Ab + (size_t)M_DIM * N_IN;             // +4 MB

    convert_A<<<M_DIM * N_IN / (256 * 4), 256, 0, stream>>>(A, Ab);
    convert_W<<<dim3(N_IN / 64, E_DIM), 256, 0, stream>>>(W, BG);
    gemm_bt<<<dim3(1024), dim3(256), 0, stream>>>(Ab, BG, out);
}

// Round 11
// 129.387 us; speedup vs baseline: 1.0262x; 1.0262x over previous
//
#include <hip/hip_runtime.h>
#include <stdint.h>

// Problem: out[m,e,k] = sum_n A[m,n] * W[e,n,k]
// == GEMM C[8192,2048] = A[8192,1024] x B[1024,2048], B[n, e*32+k] = W[e,n,k]
//
// Round-15 structure: r9 skeleton ported to v_mfma_f32_32x32x16_bf16.
// Rationale: 10 rounds eliminated schedule/LDS/occupancy/traffic; MfmaUtil
// pinned at 28-29% with 16x16x32 in every variant. 32x32x16 has a 20% higher
// FLOP/cyc ceiling (4061 vs 3378) and HALVES MFMA instruction count per FLOP
// (issue-slot relief); memory-op counts per tile unchanged -> clean isolation
// of the shape dimension. HK/AITER/hipBLASLt all use 32x32 on gfx950.
//
// Geometry: 256x256 tile, 8 waves (2x4), wave tile 128x64 = 4x2 of 32x32,
// BK=64 (4 k-steps of 16). A in double-buffered XOR-swizzled LDS (64 KB),
// B direct from L2 (BG[kg][j][8]; lane(col=l&31, k-oct=l>>5) = 16B/lane).
// B regs: 4-set rotation bf0..bf3 (s0..s3), prefetched 2 clusters ahead;
// counted-vmcnt ledger (entering c0: [bfS0·2,bfS1·2]): c0 vm(6), c1 vm(8),
// c2 vm(6), c3 vm(2) — never vm(0) mid-loop; staging proven drained at c3.
// lgkm: 4 ds/cluster, LGKM(4) drains previous cluster; LGKM(0) pre-barrier.
// M-slice XCD mapping kept (FETCH 68->24.6 MB proven in r9).
// C/D 32x32 layout: col = lane&31, row = (reg&3)+8*(reg>>2)+4*(lane>>5).

#define M_DIM 8192
#define N_IN  1024   // reduction dim
#define E_DIM 64
#define K_DIM 32
#define J_DIM 2048   // E*K output columns

typedef __attribute__((ext_vector_type(8))) __bf16 bf16x8;
typedef __attribute__((ext_vector_type(16))) float floatx16;
typedef __attribute__((address_space(3))) unsigned short lds_u16;

__device__ inline unsigned short f2bf(float f) {
    union { float f; unsigned u; } v; v.f = f;
    unsigned u = v.u;
    u += 0x7fff + ((u >> 16) & 1);   // round-to-nearest-even
    return (unsigned short)(u >> 16);
}

// A [8192,1024] f32 -> Ab bf16 (same row-major layout). 4 elements/thread.
__global__ __launch_bounds__(256) void convert_A(const float* __restrict__ A,
                                                 unsigned short* __restrict__ Ab) {
    size_t i = (size_t)blockIdx.x * 256 + threadIdx.x;
    const float4 v = ((const float4*)A)[i];
    ushort4 o;
    o.x = f2bf(v.x); o.y = f2bf(v.y); o.z = f2bf(v.z); o.w = f2bf(v.w);
    ((ushort4*)Ab)[i] = o;
}

// W [64][1024][32] f32 -> BG[kgroup=n>>3][j=e*32+k][t=n&7] bf16  (128 x 2048 x 8).
__global__ __launch_bounds__(256) void convert_W(const float* __restrict__ W,
                                                 unsigned short* __restrict__ BG) {
    const int t   = threadIdx.x;
    const int e   = blockIdx.y;        // 0..63
    const int n0  = blockIdx.x * 64;   // 16 slabs
    const int k   = t & 31;
    const int oct = t >> 5;            // 8 octets of n within the slab
    const float* Wp = W + ((size_t)e * N_IN + n0 + oct * 8) * K_DIM + k;
    unsigned short tmp[8];
#pragma unroll
    for (int u = 0; u < 8; ++u) tmp[u] = f2bf(Wp[(size_t)u * K_DIM]);  // coalesced per u
    unsigned short* out = BG + ((size_t)((n0 >> 3) + oct) * J_DIM + e * K_DIM + k) * 8;
    ushort4 lo, hi;
    lo.x = tmp[0]; lo.y = tmp[1]; lo.z = tmp[2]; lo.w = tmp[3];
    hi.x = tmp[4]; hi.y = tmp[5]; hi.z = tmp[6]; hi.w = tmp[7];
    ((ushort4*)out)[0] = lo;
    ((ushort4*)out)[1] = hi;
}

#define GLDS(SRC, DST)                                                          \
    __builtin_amdgcn_global_load_lds(                                           \
        (const __attribute__((address_space(1))) unsigned int*)(SRC),           \
        (__attribute__((address_space(3))) unsigned int*)(DST), 16, 0, 0)

// Stage A row-half HALF (128 rows x 64 k) of K-tile T1 into LDS buffer NA.
#define STAGE_A(NA, T1, HALF)                                                   \
    { _Pragma("unroll")                                                         \
      for (int c = 0; c < 2; ++c)                                               \
          GLDS(gA0 + (size_t)((HALF) * 128 + c * 64) * N_IN + (size_t)(T1) * 64,\
               (NA) + (HALF) * 8192 + c * 4096 + wave * 512); }

#define WAIT_VM(N) asm volatile("s_waitcnt vmcnt(" #N ")" ::: "memory")
#define LGKM(N)    asm volatile("s_waitcnt lgkmcnt(" #N ")" ::: "memory")
#define SB()       __builtin_amdgcn_sched_barrier(0)

// A fragments for k-step S (4 m-subtiles of 32 rows), ds_read_b128 each.
// lane: row = base + (l&31), k-octet = S*2 + (l>>5), slot XOR row&7 (= l&7).
#define RD_A32(DST, CA, S)                                                      \
    { _Pragma("unroll")                                                         \
      for (int mi = 0; mi < 4; ++mi)                                            \
          DST[mi] = *(const __attribute__((address_space(3))) bf16x8*)          \
                    ((CA) + arow32 + mi * 2048 + ((((S) * 2 + hi) ^ l7) << 3)); }

// B fragments for K-tile T, k-step S (2 j-subtiles of 32 cols), 16B/lane.
#define RD_B32(DST, T, S)                                                       \
    { const int kg_ = (T) * 8 + (S) * 2 + hi;                                   \
      _Pragma("unroll")                                                         \
      for (int ji = 0; ji < 2; ++ji)                                            \
          DST[ji] = *(const bf16x8*)(BG + ((size_t)kg_ * J_DIM + jcolB + ji * 32) * 8); }

// 8-MFMA cluster (one k-step: 4 m x 2 j of 32x32x16), T5 setprio wrap.
#define MFMA8(AF, BF)                                                           \
    { __builtin_amdgcn_s_setprio(1);                                            \
      _Pragma("unroll")                                                         \
      for (int mi = 0; mi < 4; ++mi) {                                          \
          _Pragma("unroll")                                                     \
          for (int ji = 0; ji < 2; ++ji)                                        \
              acc[mi][ji] = __builtin_amdgcn_mfma_f32_32x32x16_bf16(            \
                  AF[mi], BF[ji], acc[mi][ji], 0, 0, 0);                        \
      }                                                                         \
      __builtin_amdgcn_s_setprio(0); }

__global__ __launch_bounds__(512, 1) void gemm_bt(const unsigned short* __restrict__ Ab,
                                                  const unsigned short* __restrict__ BG,
                                                  float* __restrict__ C) {
    __shared__ unsigned short As0[16384];   // A tile buf0: [256 rows][8 grp][8]
    __shared__ unsigned short As1[16384];

    const int tid  = threadIdx.x;
    const int wave = tid >> 6;       // 0..7
    const int lane = tid & 63;
    const int wm = wave >> 2;        // 0..1  (M-half of 256)
    const int wn = wave & 3;         // 0..3  (N-quarter of 256)

    // M-slice XCD ownership: XCD x (= orig%8) owns m-tiles [4x, 4x+4):
    // A slice 2 MB -> L2-resident. j walks slowest within an XCD.
    const int orig = blockIdx.x;     // 256 blocks = 32 m x 8 j
    const int xcd  = orig & 7;
    const int s    = orig >> 3;
    const int m0 = (xcd * 4 + (s & 3)) * 256;
    const int j0 = (s >> 2) * 256;

    const int l7 = lane & 7, lrow8 = lane >> 3;
    const int l31 = lane & 31, hi = lane >> 5;

    // A staging: lane l covers LDS slot (row=l>>3, grp=l&7), fetching
    // pre-swizzled global group (l&7)^(l>>3).
    const unsigned short* gA0 = Ab + (size_t)(m0 + wave * 8 + lrow8) * N_IN
                                   + ((l7 ^ lrow8) << 3);
    const int jcolB = j0 + wn * 64 + l31;     // per-lane B column

    lds_u16* cA = (lds_u16*)As0;
    lds_u16* nA = (lds_u16*)As1;

    floatx16 acc[4][2];
#pragma unroll
    for (int i = 0; i < 4; ++i)
#pragma unroll
        for (int j = 0; j < 2; ++j) acc[i][j] = (floatx16)(0.0f);

    // Fragment-read addressing: A row base (shorts); row&7 == l7 (mi*32 ≡ 0 mod 8).
    const int arow32 = (wm * 128 + l31) * 64;

    bf16x8 afA[4], afB[4], bf0[2], bf1[2], bf2[2], bf3[2];

    // --- prologue: stage A(0); prefetch B(0,s0/s1); barrier; read A(s0) -----
    STAGE_A(cA, 0, 0);
    STAGE_A(cA, 0, 1); SB();
    RD_B32(bf0, 0, 0); SB();
    RD_B32(bf1, 0, 1); SB();
    WAIT_VM(4); SB();                 // staging drained (bf0,bf1 in flight)
    __builtin_amdgcn_s_barrier(); SB();
    RD_A32(afA, cA, 0); SB();

    // --- main loop: 15 tiles, clusters c0..c3 = k-steps s0..s3 --------------
    for (int t = 0; t < 15; ++t) {
        // c0 (s0: afA,bf0) | issue A(s1), stage#1(t+1), B(t,s2)
        RD_A32(afB, cA, 1); SB();
        STAGE_A(nA, t + 1, 0); SB();
        RD_B32(bf2, t, 2); SB();
        LGKM(4);                      // afA ready
        WAIT_VM(6); SB();             // bf0 ready; [bf1·2,stg2,bf2·2] left
        MFMA8(afA, bf0);

        // c1 (s1: afB,bf1) | issue A(s2), stage#2(t+1), B(t,s3)
        RD_A32(afA, cA, 2); SB();
        STAGE_A(nA, t + 1, 1); SB();
        RD_B32(bf3, t, 3); SB();
        LGKM(4);                      // afB ready
        WAIT_VM(8); SB();             // bf1 ready; [stg2,bf2·2,stg2,bf3·2] left
        MFMA8(afB, bf1);

        // c2 (s2: afA,bf2) | issue A(s3), B(t+1,s0)
        RD_A32(afB, cA, 3); SB();
        RD_B32(bf0, t + 1, 0); SB();
        LGKM(4);                      // afA ready
        WAIT_VM(6); SB();             // bf2 ready (stage#1 drained too)
        MFMA8(afA, bf2);

        // c3 (s3: afB,bf3) | drain, barrier, swap, issue next-tile A(s0)+B(s1)
        LGKM(0);                      // all own ds_reads done (afB incl.)
        WAIT_VM(2); SB();             // bf3 ready + ALL staging drained;
                                      // bf0(t+1) rides over the barrier
        __builtin_amdgcn_s_barrier(); SB();
        { lds_u16* sw = cA; cA = nA; nA = sw; }
        RD_A32(afA, cA, 0); SB();
        RD_B32(bf1, t + 1, 1); SB();
        MFMA8(afB, bf3);
    }

    // --- tail tile 15 (no staging, no t+1 B) --------------------------------
    RD_A32(afB, cA, 1); SB();
    RD_B32(bf2, 15, 2); SB();
    LGKM(4);
    WAIT_VM(4); SB();                 // bf0 ready
    MFMA8(afA, bf0);
    RD_A32(afA, cA, 2); SB();
    RD_B32(bf3, 15, 3); SB();
    LGKM(4);
    WAIT_VM(4); SB();                 // bf1 ready
    MFMA8(afB, bf1);
    RD_A32(afB, cA, 3); SB();
    LGKM(4);
    WAIT_VM(2); SB();                 // bf2 ready
    MFMA8(afA, bf2);
    LGKM(0);
    WAIT_VM(0); SB();                 // bf3 ready
    MFMA8(afB, bf3);

    // Epilogue: 32x32 C/D layout: col = lane&31, row = (reg&3)+8*(reg>>2)+4*hi
#pragma unroll
    for (int mi = 0; mi < 4; ++mi) {
#pragma unroll
        for (int ji = 0; ji < 2; ++ji) {
            float* Cp = C + (size_t)(m0 + wm * 128 + mi * 32 + 4 * hi) * J_DIM
                          + (j0 + wn * 64 + ji * 32 + l31);
#pragma unroll
            for (int g = 0; g < 4; ++g)
#pragma unroll
                for (int r = 0; r < 4; ++r)
                    Cp[(size_t)(g * 8 + r) * J_DIM] = acc[mi][ji][g * 4 + r];
        }
    }
}

extern "C" void kernel_launch(void* const* d_in, const int* in_sizes, int n_in,
                              void* d_out, int out_size, void* d_ws, size_t ws_size,
                              hipStream_t stream) {
    const float* A = (const float*)d_in[0];   // [8192,1024]
    const float* W = (const float*)d_in[1];   // [64,1024,32]
    float* out = (float*)d_out;               // [8192,64,32] == [8192,2048]

    unsigned short* Ab = (unsigned short*)d_ws;                 // 16 MB
    unsigned short* BG = Ab + (size_t)M_DIM * N_IN;             // +4 MB

    convert_A<<<M_DIM * N_IN / (256 * 4), 256, 0, stream>>>(A, Ab);
    convert_W<<<dim3(N_IN / 64, E_DIM), 256, 0, stream>>>(W, BG);
    gemm_bt<<<dim3(256), dim3(512), 0, stream>>>(Ab, BG, out);
}